// Round 13
// baseline (613.832 us; speedup 1.0000x reference)
//
#include <hip/hip_runtime.h>

typedef short bf16x8 __attribute__((ext_vector_type(8)));
typedef float f32x4 __attribute__((ext_vector_type(4)));

constexpr int N_NODES = 50000;
constexpr int F_IN    = 512;
constexpr int F_HID   = 256;
constexpr int F_OUT   = 40;
constexpr int SCAN_BLOCKS = (N_NODES + 255) / 256;   // 196

__device__ __forceinline__ float bf2f(unsigned short u) {
  return __uint_as_float(((unsigned)u) << 16);
}
__device__ __forceinline__ unsigned short f2bf(float f) {
  unsigned x = __float_as_uint(f);
  x += 0x7FFFu + ((x >> 16) & 1u);      // RNE
  return (unsigned short)(x >> 16);
}

// pack 8 fp32 -> bf16x8 (RNE)
__device__ __forceinline__ bf16x8 cvt8(f32x4 a, f32x4 b) {
  bf16x8 o;
  o[0] = (short)f2bf(a[0]); o[1] = (short)f2bf(a[1]);
  o[2] = (short)f2bf(a[2]); o[3] = (short)f2bf(a[3]);
  o[4] = (short)f2bf(b[0]); o[5] = (short)f2bf(b[1]);
  o[6] = (short)f2bf(b[2]); o[7] = (short)f2bf(b[3]);
  return o;
}

// JAX threefry2x32, key=(0,42), PARTITIONABLE counter scheme (verified R8):
// element i -> pair (0, i); output = x0_final ^ x1_final; keep iff bit31==0.
__device__ __forceinline__ unsigned tf_rotl(unsigned x, int d) {
  return (x << d) | (x >> (32 - d));
}
__device__ __forceinline__ unsigned threefry_bits(unsigned i) {
  const unsigned k0 = 0u, k1 = 42u, k2 = 0x1BD11BDAu ^ 0u ^ 42u;
  unsigned x0 = 0u + k0, x1 = i + k1;
#define TF_R(r) { x0 += x1; x1 = tf_rotl(x1, (r)) ^ x0; }
  TF_R(13) TF_R(15) TF_R(26) TF_R(6)   x0 += k1; x1 += k2 + 1u;
  TF_R(17) TF_R(29) TF_R(16) TF_R(24)  x0 += k2; x1 += k0 + 2u;
  TF_R(13) TF_R(15) TF_R(26) TF_R(6)   x0 += k0; x1 += k1 + 3u;
  TF_R(17) TF_R(29) TF_R(16) TF_R(24)  x0 += k1; x1 += k2 + 4u;
  TF_R(13) TF_R(15) TF_R(26) TF_R(6)   x0 += k2; x1 += k0 + 5u;
#undef TF_R
  return x0 ^ x1;
}

__global__ void k_zero(int* __restrict__ p, int n) {
  int i = blockIdx.x * 256 + threadIdx.x;
  if (i < n) p[i] = 0;
}

// ---------------- CSR build (plain) ----------------
__global__ void k_hist(const int* __restrict__ dst, int* __restrict__ deg, int E) {
  int e = blockIdx.x * 256 + threadIdx.x;
  if (e < E) atomicAdd(&deg[dst[e]], 1);
}

__global__ __launch_bounds__(256) void k_scan_part(const int* __restrict__ deg,
                                                   int* __restrict__ bsum) {
  __shared__ int red[256];
  int t = threadIdx.x;
  int i = blockIdx.x * 256 + t;
  red[t] = (i < N_NODES) ? deg[i] : 0;
  __syncthreads();
#pragma unroll
  for (int off = 128; off > 0; off >>= 1) {
    if (t < off) red[t] += red[t + off];
    __syncthreads();
  }
  if (t == 0) bsum[blockIdx.x] = red[0];
}

__global__ __launch_bounds__(256) void k_scan_base(int* __restrict__ bsum,
                                                   int* __restrict__ offs) {
  __shared__ int sh[256];
  int t = threadIdx.x;
  int v = (t < SCAN_BLOCKS) ? bsum[t] : 0;
  sh[t] = v;
  __syncthreads();
#pragma unroll
  for (int off = 1; off < 256; off <<= 1) {
    int x = (t >= off) ? sh[t - off] : 0;
    __syncthreads();
    sh[t] += x;
    __syncthreads();
  }
  if (t < SCAN_BLOCKS) bsum[t] = sh[t] - v;        // exclusive block base
  if (t == 255) offs[N_NODES] = sh[255];           // == E
}

__global__ __launch_bounds__(256) void k_scan_final(int* __restrict__ deg,
                                                    const int* __restrict__ bsum,
                                                    int* __restrict__ offs) {
  __shared__ int sh[256];
  int t = threadIdx.x;
  int i = blockIdx.x * 256 + t;
  int v = (i < N_NODES) ? deg[i] : 0;
  sh[t] = v;
  __syncthreads();
#pragma unroll
  for (int off = 1; off < 256; off <<= 1) {
    int x = (t >= off) ? sh[t - off] : 0;
    __syncthreads();
    sh[t] += x;
    __syncthreads();
  }
  if (i < N_NODES) {
    offs[i] = bsum[blockIdx.x] + sh[t] - v;        // exclusive
    deg[i] = 0;                                    // becomes scatter cursor
  }
}

// packed edge: (src << 16) | bf16(weight)  (standalone, fallback path)
__global__ void k_scatter(const int* __restrict__ src, const int* __restrict__ dst,
                          const float* __restrict__ w,
                          const int* __restrict__ offs, int* __restrict__ cursor,
                          unsigned* __restrict__ ep, int E) {
  int e = blockIdx.x * 256 + threadIdx.x;
  if (e < E) {
    int d = dst[e];
    int pos = offs[d] + atomicAdd(&cursor[d], 1);
    if (pos >= 0 && pos < E)
      ep[pos] = ((unsigned)src[e] << 16) | (unsigned)f2bf(w[e]);
  }
}

// ---------------- W1 -> bf16 transpose (standalone, fallback path) -----------
__global__ void k_wt(const float* __restrict__ W1, unsigned short* __restrict__ wT) {
  int i = blockIdx.x * 256 + threadIdx.x;      // 131072 elements
  if (i < F_IN * F_HID) {
    int c = i >> 9, k = i & 511;
    wT[i] = f2bf(W1[(size_t)k * F_HID + c]);
  }
}

// ---------------- packed launch 1: k_wt ∥ k_hist (independent) ---------------
__global__ void k_wt_hist(const float* __restrict__ W1, unsigned short* __restrict__ wT,
                          const int* __restrict__ dst, int* __restrict__ deg,
                          int E, int wtBlocks) {
  int bid = blockIdx.x;
  if (bid < wtBlocks) {
    int i = bid * 256 + threadIdx.x;
    if (i < F_IN * F_HID) {
      int c = i >> 9, k = i & 511;
      wT[i] = f2bf(W1[(size_t)k * F_HID + c]);
    }
  } else {
    int e = (bid - wtBlocks) * 256 + threadIdx.x;
    if (e < E) atomicAdd(&deg[dst[e]], 1);
  }
}

// ---------------- layer-1 MFMA GEMM (standalone, fallback per-half) ----------
__global__ __launch_bounds__(256, 4) void k_gemm1(const float* __restrict__ X,
                                                  const unsigned short* __restrict__ wT,
                                                  unsigned short* __restrict__ out,
                                                  int ldh, int half) {
  int t = threadIdx.x;
  int wave = t >> 6, lane = t & 63, q = lane >> 4, r = lane & 15;
  int halfsel = half, tile = blockIdx.x;
  int r0 = tile * 64;
  int colbase = (ldh == 256) ? halfsel * 128 : 0;
  int arow = r0 + wave * 16 + r;
  if (arow > N_NODES - 1) arow = N_NODES - 1;
  const float* xrow = X + (size_t)arow * F_IN + q * 8;
  const unsigned short* bl = wT + (size_t)halfsel * 128 * F_IN + (size_t)r * F_IN + q * 8;
  f32x4 acc[8];
#pragma unroll
  for (int n = 0; n < 8; ++n) acc[n] = (f32x4){0.f, 0.f, 0.f, 0.f};
  bf16x8 BA[8], BB[8];
#pragma unroll
  for (int n = 0; n < 8; ++n)
    BA[n] = *(const bf16x8*)(bl + (size_t)n * 16 * F_IN);
#pragma unroll
  for (int k0 = 0; k0 < F_IN; k0 += 64) {
    f32x4 a0 = *(const f32x4*)(xrow + k0);
    f32x4 a1 = *(const f32x4*)(xrow + k0 + 4);
    f32x4 a2 = *(const f32x4*)(xrow + k0 + 32);
    f32x4 a3 = *(const f32x4*)(xrow + k0 + 36);
    bf16x8 A0 = cvt8(a0, a1);
    bf16x8 A1 = cvt8(a2, a3);
#pragma unroll
    for (int n = 0; n < 8; ++n)
      BB[n] = *(const bf16x8*)(bl + (size_t)n * 16 * F_IN + k0 + 32);
#pragma unroll
    for (int n = 0; n < 8; ++n)
      acc[n] = __builtin_amdgcn_mfma_f32_16x16x32_bf16(A0, BA[n], acc[n], 0, 0, 0);
    if (k0 + 64 < F_IN) {
#pragma unroll
      for (int n = 0; n < 8; ++n)
        BA[n] = *(const bf16x8*)(bl + (size_t)n * 16 * F_IN + k0 + 64);
    }
#pragma unroll
    for (int n = 0; n < 8; ++n)
      acc[n] = __builtin_amdgcn_mfma_f32_16x16x32_bf16(A1, BB[n], acc[n], 0, 0, 0);
  }
  // Store tt-outer/n-inner: each row's 8 n-pieces issue consecutively so its
  // 2 cache lines complete within 8 store instrs (write-combine friendly).
  int mrow = r0 + wave * 16 + q * 4;
#pragma unroll
  for (int tt = 0; tt < 4; ++tt) {
    int row = mrow + tt;
    if (row < N_NODES) {
#pragma unroll
      for (int n = 0; n < 8; ++n)
        out[(size_t)row * ldh + colbase + n * 16 + r] = f2bf(acc[n][tt]);
    }
  }
}

// ---------------- packed launch 2: scatter ∥ fused gemm1 ---------------------
// Scatter blocks FIRST (bid < scatBlocks): 6250 short blocks drain in the
// first ~30us, so gemm epilogues (late in each gemm block) write h1 without
// the L2 being churned by random ep writes (R12 counters showed 125MB h1
// write traffic vs 32MB expected = partial-line eviction amplification).
// gemm blocks: R2-proven loop + R8 XCD half-pairing, ldh=256.
__global__ __launch_bounds__(256, 4) void k_gemm1_scatter(
    const float* __restrict__ X, const unsigned short* __restrict__ wT,
    unsigned short* __restrict__ out,
    const int* __restrict__ src, const int* __restrict__ dst,
    const float* __restrict__ w, const int* __restrict__ offs,
    int* __restrict__ cursor, unsigned* __restrict__ ep,
    int E, int scatBlocks) {
  int bid = blockIdx.x;
  if (bid < scatBlocks) {
    int e = bid * 256 + threadIdx.x;
    if (e < E) {
      int d = dst[e];
      int pos = offs[d] + atomicAdd(&cursor[d], 1);
      if (pos >= 0 && pos < E)
        ep[pos] = ((unsigned)src[e] << 16) | (unsigned)f2bf(w[e]);
    }
    return;
  }
  int gbid = bid - scatBlocks;
  int t = threadIdx.x;
  int wave = t >> 6, lane = t & 63, q = lane >> 4, r = lane & 15;
  int halfsel = (gbid >> 3) & 1;
  int tile = ((gbid >> 4) << 3) + (gbid & 7);
  int r0 = tile * 64;
  int colbase = halfsel * 128;
  int arow = r0 + wave * 16 + r;               // this lane's A row
  if (arow > N_NODES - 1) arow = N_NODES - 1;  // clamp (results discarded)
  const float* xrow = X + (size_t)arow * F_IN + q * 8;
  const unsigned short* bl = wT + (size_t)halfsel * 128 * F_IN + (size_t)r * F_IN + q * 8;
  f32x4 acc[8];
#pragma unroll
  for (int n = 0; n < 8; ++n) acc[n] = (f32x4){0.f, 0.f, 0.f, 0.f};

  bf16x8 BA[8], BB[8];
#pragma unroll
  for (int n = 0; n < 8; ++n)
    BA[n] = *(const bf16x8*)(bl + (size_t)n * 16 * F_IN);

#pragma unroll
  for (int k0 = 0; k0 < F_IN; k0 += 64) {
    f32x4 a0 = *(const f32x4*)(xrow + k0);
    f32x4 a1 = *(const f32x4*)(xrow + k0 + 4);
    f32x4 a2 = *(const f32x4*)(xrow + k0 + 32);
    f32x4 a3 = *(const f32x4*)(xrow + k0 + 36);
    bf16x8 A0 = cvt8(a0, a1);
    bf16x8 A1 = cvt8(a2, a3);
#pragma unroll
    for (int n = 0; n < 8; ++n)
      BB[n] = *(const bf16x8*)(bl + (size_t)n * 16 * F_IN + k0 + 32);
#pragma unroll
    for (int n = 0; n < 8; ++n)
      acc[n] = __builtin_amdgcn_mfma_f32_16x16x32_bf16(A0, BA[n], acc[n], 0, 0, 0);
    if (k0 + 64 < F_IN) {
#pragma unroll
      for (int n = 0; n < 8; ++n)
        BA[n] = *(const bf16x8*)(bl + (size_t)n * 16 * F_IN + k0 + 64);
    }
#pragma unroll
    for (int n = 0; n < 8; ++n)
      acc[n] = __builtin_amdgcn_mfma_f32_16x16x32_bf16(A1, BB[n], acc[n], 0, 0, 0);
  }
  // D: col = n*16 + r, row = wave*16 + q*4 + tt  (verified layout)
  // Store tt-outer/n-inner (write-combine friendly; see R12 post-mortem).
  int mrow = r0 + wave * 16 + q * 4;
#pragma unroll
  for (int tt = 0; tt < 4; ++tt) {
    int row = mrow + tt;
    if (row < N_NODES) {
#pragma unroll
      for (int n = 0; n < 8; ++n)
        out[(size_t)row * 256 + colbase + n * 16 + r] = f2bf(acc[n][tt]);
    }
  }
}

// ---------------- FUSED single-pass agg1 + gemm2 (full 256 cols) -------------
// Proven R5 form (173 us, structural floor: 340MB L2-miss @ ~2TB/s fabric on
// a random-graph gather -- R9's locality attempt was neutral). 4 scalar ep
// loads + 4 independent ushort4 gathers in flight; W2 staged bf16 in LDS
// (keeps VGPR at 40; removing it collapsed gather MLP in R6, 173->338 us).
__global__ __launch_bounds__(256) void k_agg1f(const ushort4* __restrict__ h14,
                                               const int* __restrict__ offs,
                                               const unsigned* __restrict__ ep,
                                               const float* __restrict__ b1,
                                               const float* __restrict__ W2,
                                               float* __restrict__ o1) {
  __shared__ unsigned short w2h[F_HID * F_OUT];  // 20 KB (row-major copy)
  __shared__ float hrow[4][F_HID];               // 4 KB
  int t = threadIdx.x;
  for (int i = t; i < F_HID * F_OUT; i += 256)
    w2h[i] = f2bf(W2[i]);                        // same layout, just bf16
  int wave = t >> 6, lane = t & 63;
  int wid = blockIdx.x * 4 + wave;
  int s0 = offs[wid], s1 = offs[wid + 1];
  float a0 = 0.f, a1 = 0.f, a2 = 0.f, a3 = 0.f;
  int e = s0;
  for (; e + 4 <= s1; e += 4) {
    unsigned p0 = ep[e], p1 = ep[e + 1], p2 = ep[e + 2], p3 = ep[e + 3];
    ushort4 v0 = h14[(size_t)(p0 >> 16) * 64 + lane];
    ushort4 v1 = h14[(size_t)(p1 >> 16) * 64 + lane];
    ushort4 v2 = h14[(size_t)(p2 >> 16) * 64 + lane];
    ushort4 v3 = h14[(size_t)(p3 >> 16) * 64 + lane];
    float w0 = bf2f((unsigned short)p0), w1 = bf2f((unsigned short)p1);
    float w2 = bf2f((unsigned short)p2), w3 = bf2f((unsigned short)p3);
    a0 = fmaf(w0, bf2f(v0.x), a0); a1 = fmaf(w0, bf2f(v0.y), a1);
    a2 = fmaf(w0, bf2f(v0.z), a2); a3 = fmaf(w0, bf2f(v0.w), a3);
    a0 = fmaf(w1, bf2f(v1.x), a0); a1 = fmaf(w1, bf2f(v1.y), a1);
    a2 = fmaf(w1, bf2f(v1.z), a2); a3 = fmaf(w1, bf2f(v1.w), a3);
    a0 = fmaf(w2, bf2f(v2.x), a0); a1 = fmaf(w2, bf2f(v2.y), a1);
    a2 = fmaf(w2, bf2f(v2.z), a2); a3 = fmaf(w2, bf2f(v2.w), a3);
    a0 = fmaf(w3, bf2f(v3.x), a0); a1 = fmaf(w3, bf2f(v3.y), a1);
    a2 = fmaf(w3, bf2f(v3.z), a2); a3 = fmaf(w3, bf2f(v3.w), a3);
  }
  for (; e < s1; ++e) {
    unsigned pe = ep[e];
    float w = bf2f((unsigned short)pe);
    ushort4 v = h14[(size_t)(pe >> 16) * 64 + lane];
    a0 = fmaf(w, bf2f(v.x), a0);
    a1 = fmaf(w, bf2f(v.y), a1);
    a2 = fmaf(w, bf2f(v.z), a2);
    a3 = fmaf(w, bf2f(v.w), a3);
  }
  int c0 = lane * 4;
  unsigned base = (unsigned)wid * 256u + (unsigned)c0;
  float r0 = fmaxf(a0 + b1[c0 + 0], 0.f);
  float r1 = fmaxf(a1 + b1[c0 + 1], 0.f);
  float r2 = fmaxf(a2 + b1[c0 + 2], 0.f);
  float r3 = fmaxf(a3 + b1[c0 + 3], 0.f);
  hrow[wave][c0 + 0] = (threefry_bits(base + 0u) >> 31) ? 0.f : r0 * 2.f;
  hrow[wave][c0 + 1] = (threefry_bits(base + 1u) >> 31) ? 0.f : r1 * 2.f;
  hrow[wave][c0 + 2] = (threefry_bits(base + 2u) >> 31) ? 0.f : r2 * 2.f;
  hrow[wave][c0 + 3] = (threefry_bits(base + 3u) >> 31) ? 0.f : r3 * 2.f;
  __syncthreads();                             // w2h + hrow visibility
  if (lane < F_OUT) {
    float acc = 0.f;
#pragma unroll 8
    for (int k = 0; k < F_HID; ++k)
      acc = fmaf(hrow[wave][k], bf2f(w2h[k * F_OUT + lane]), acc);
    o1[(size_t)wid * F_OUT + lane] = acc;      // single pass: direct store
  }
}

// ---------------- fallback: per-half agg1 (o1 accumulates) -------------------
__global__ __launch_bounds__(256) void k_agg1h(const ushort2* __restrict__ h1h2,
                                               const int* __restrict__ offs,
                                               const unsigned* __restrict__ ep,
                                               const float* __restrict__ b1,
                                               const float* __restrict__ W2,
                                               float* __restrict__ o1, int half) {
  __shared__ unsigned short w2h[128 * F_OUT];  // 10 KB
  __shared__ float hrow[4][128];               // 2 KB
  int t = threadIdx.x;
  for (int i = t; i < 128 * F_OUT; i += 256) {
    int k = i / F_OUT, j = i - k * F_OUT;
    w2h[i] = f2bf(W2[(size_t)(half * 128 + k) * F_OUT + j]);
  }
  int wave = t >> 6, lane = t & 63;
  int wid = blockIdx.x * 4 + wave;
  int s0 = offs[wid], s1 = offs[wid + 1];
  float a0 = 0.f, a1 = 0.f;
  int e = s0;
  for (; e + 4 <= s1; e += 4) {
    unsigned p0 = ep[e], p1 = ep[e + 1], p2 = ep[e + 2], p3 = ep[e + 3];
    ushort2 v0 = h1h2[(size_t)(p0 >> 16) * 64 + lane];
    ushort2 v1 = h1h2[(size_t)(p1 >> 16) * 64 + lane];
    ushort2 v2 = h1h2[(size_t)(p2 >> 16) * 64 + lane];
    ushort2 v3 = h1h2[(size_t)(p3 >> 16) * 64 + lane];
    float w0 = bf2f((unsigned short)p0), w1 = bf2f((unsigned short)p1);
    float w2 = bf2f((unsigned short)p2), w3 = bf2f((unsigned short)p3);
    a0 = fmaf(w0, bf2f(v0.x), a0); a1 = fmaf(w0, bf2f(v0.y), a1);
    a0 = fmaf(w1, bf2f(v1.x), a0); a1 = fmaf(w1, bf2f(v1.y), a1);
    a0 = fmaf(w2, bf2f(v2.x), a0); a1 = fmaf(w2, bf2f(v2.y), a1);
    a0 = fmaf(w3, bf2f(v3.x), a0); a1 = fmaf(w3, bf2f(v3.y), a1);
  }
  for (; e < s1; ++e) {
    unsigned pe = ep[e];
    float w = bf2f((unsigned short)pe);
    ushort2 v = h1h2[(size_t)(pe >> 16) * 64 + lane];
    a0 = fmaf(w, bf2f(v.x), a0);
    a1 = fmaf(w, bf2f(v.y), a1);
  }
  int c0 = lane * 2;
  int gc = half * 128 + c0;
  float r0 = fmaxf(a0 + b1[gc + 0], 0.f);
  float r1 = fmaxf(a1 + b1[gc + 1], 0.f);
  unsigned base = (unsigned)wid * 256u + (unsigned)gc;
  r0 = (threefry_bits(base + 0u) >> 31) ? 0.f : r0 * 2.f;   // keep iff u<0.5
  r1 = (threefry_bits(base + 1u) >> 31) ? 0.f : r1 * 2.f;
  hrow[wave][c0 + 0] = r0;
  hrow[wave][c0 + 1] = r1;
  __syncthreads();                             // w2h + hrow visibility
  if (lane < F_OUT) {
    float acc = 0.f;
#pragma unroll 8
    for (int k = 0; k < 128; ++k)
      acc = fmaf(hrow[wave][k], bf2f(w2h[k * F_OUT + lane]), acc);
    o1[(size_t)wid * F_OUT + lane] += acc;
  }
}

// ---------------- agg2: out[d] = sum_e w*o1[src] + b2 (fp32 out) --------------
// 8 scalar ep loads + 8 independent gathers in flight (R11, +9us).
__global__ __launch_bounds__(256) void k_agg2(const float* __restrict__ o1,
                                              const int* __restrict__ offs,
                                              const unsigned* __restrict__ ep,
                                              const float* __restrict__ b2,
                                              float* __restrict__ out) {
  int wid  = (blockIdx.x << 2) + (threadIdx.x >> 6);
  int lane = threadIdx.x & 63;
  if (lane >= F_OUT) return;
  int s0 = offs[wid], s1 = offs[wid + 1];
  float bias = b2[lane];
  float acc = 0.f;
  int e = s0;
  for (; e + 8 <= s1; e += 8) {
    unsigned p0 = ep[e],     p1 = ep[e + 1], p2 = ep[e + 2], p3 = ep[e + 3];
    unsigned p4 = ep[e + 4], p5 = ep[e + 5], p6 = ep[e + 6], p7 = ep[e + 7];
    float g0 = o1[(size_t)(p0 >> 16) * F_OUT + lane];
    float g1 = o1[(size_t)(p1 >> 16) * F_OUT + lane];
    float g2 = o1[(size_t)(p2 >> 16) * F_OUT + lane];
    float g3 = o1[(size_t)(p3 >> 16) * F_OUT + lane];
    float g4 = o1[(size_t)(p4 >> 16) * F_OUT + lane];
    float g5 = o1[(size_t)(p5 >> 16) * F_OUT + lane];
    float g6 = o1[(size_t)(p6 >> 16) * F_OUT + lane];
    float g7 = o1[(size_t)(p7 >> 16) * F_OUT + lane];
    acc = fmaf(bf2f((unsigned short)p0), g0, acc);
    acc = fmaf(bf2f((unsigned short)p1), g1, acc);
    acc = fmaf(bf2f((unsigned short)p2), g2, acc);
    acc = fmaf(bf2f((unsigned short)p3), g3, acc);
    acc = fmaf(bf2f((unsigned short)p4), g4, acc);
    acc = fmaf(bf2f((unsigned short)p5), g5, acc);
    acc = fmaf(bf2f((unsigned short)p6), g6, acc);
    acc = fmaf(bf2f((unsigned short)p7), g7, acc);
  }
  if (e + 4 <= s1) {
    unsigned p0 = ep[e], p1 = ep[e + 1], p2 = ep[e + 2], p3 = ep[e + 3];
    float g0 = o1[(size_t)(p0 >> 16) * F_OUT + lane];
    float g1 = o1[(size_t)(p1 >> 16) * F_OUT + lane];
    float g2 = o1[(size_t)(p2 >> 16) * F_OUT + lane];
    float g3 = o1[(size_t)(p3 >> 16) * F_OUT + lane];
    acc = fmaf(bf2f((unsigned short)p0), g0, acc);
    acc = fmaf(bf2f((unsigned short)p1), g1, acc);
    acc = fmaf(bf2f((unsigned short)p2), g2, acc);
    acc = fmaf(bf2f((unsigned short)p3), g3, acc);
    e += 4;
  }
  for (; e < s1; ++e) {
    unsigned pe = ep[e];
    acc = fmaf(bf2f((unsigned short)pe), o1[(size_t)(pe >> 16) * F_OUT + lane], acc);
  }
  out[(size_t)wid * F_OUT + lane] = acc + bias;
}

extern "C" void kernel_launch(void* const* d_in, const int* in_sizes, int n_in,
                              void* d_out, int out_size, void* d_ws, size_t ws_size,
                              hipStream_t stream) {
  const float* x    = (const float*)d_in[0];
  const int*   esrc = (const int*)d_in[1];
  const int*   edst = (const int*)d_in[2];
  const float* ew   = (const float*)d_in[3];
  const float* W1   = (const float*)d_in[4];
  const float* b1   = (const float*)d_in[5];
  const float* W2   = (const float*)d_in[6];
  const float* b2   = (const float*)d_in[7];
  const int E = in_sizes[1];

  auto rup = [](size_t b) { return (b + 255) & ~(size_t)255; };
  const size_t sz_h1full = rup((size_t)N_NODES * 256 * 2);   // 25.6 MB
  const size_t sz_h1half = rup((size_t)N_NODES * 128 * 2);   // 12.8 MB
  const size_t sz_o1     = rup((size_t)N_NODES * F_OUT * 4); // 8 MB
  const size_t sz_ep     = rup((size_t)E * 4);               // 6.4 MB
  const size_t sz_wT     = rup((size_t)F_IN * F_HID * 2);    // 262 KB
  const size_t sz_offs   = rup((size_t)(N_NODES + 1) * 4);
  const size_t sz_deg    = rup((size_t)N_NODES * 4);
  const size_t sz_bsum   = rup((size_t)SCAN_BLOCKS * 4);
  const size_t tail      = sz_o1 + sz_ep + sz_wT + sz_offs + sz_deg + sz_bsum;
  const bool   fused     = ws_size >= sz_h1full + tail;      // ~40.7 MB

  char* p = (char*)d_ws;
  auto alloc = [&](size_t bytes) { char* r = p; p += bytes; return r; };
  unsigned short* h1   = (unsigned short*)alloc(fused ? sz_h1full : sz_h1half);
  float*          o1   = (float*)alloc(sz_o1);
  unsigned*       ep   = (unsigned*)alloc(sz_ep);
  unsigned short* wT   = (unsigned short*)alloc(sz_wT);
  int*            offs = (int*)alloc(sz_offs);
  int*            deg  = (int*)alloc(sz_deg);
  int*            bsum = (int*)alloc(sz_bsum);

  int eb = (E + 255) / 256;
  int gblocks = (N_NODES + 63) / 64;           // 782
  int wtB = (F_IN * F_HID + 255) / 256;        // 512

  k_zero<<<(N_NODES + 255) / 256, 256, 0, stream>>>(deg, N_NODES);

  if (fused) {
    // L1: W1-transpose ∥ degree histogram (independent)
    k_wt_hist<<<wtB + eb, 256, 0, stream>>>(W1, wT, edst, deg, E, wtB);
    // L2-4: scan chain
    k_scan_part<<<SCAN_BLOCKS, 256, 0, stream>>>(deg, bsum);
    k_scan_base<<<1, 256, 0, stream>>>(bsum, offs);
    k_scan_final<<<SCAN_BLOCKS, 256, 0, stream>>>(deg, bsum, offs);
    // L5: edge scatter (front) ∥ fused gemm1 (independent)
    int gpad = (gblocks + 7) & ~7;             // 784: bijective XCD pairing
    int gB = gpad * 2;                         // 1568 gemm blocks
    k_gemm1_scatter<<<eb + gB, 256, 0, stream>>>(x, wT, h1, esrc, edst, ew,
                                                 offs, deg, ep, E, eb);
    // L6-7
    k_agg1f<<<N_NODES / 4, 256, 0, stream>>>((const ushort4*)h1, offs, ep, b1, W2, o1);
    k_agg2<<<N_NODES / 4, 256, 0, stream>>>(o1, offs, ep, b2, (float*)d_out);
  } else {
    k_wt<<<wtB, 256, 0, stream>>>(W1, wT);
    k_hist<<<eb, 256, 0, stream>>>(edst, deg, E);
    k_scan_part<<<SCAN_BLOCKS, 256, 0, stream>>>(deg, bsum);
    k_scan_base<<<1, 256, 0, stream>>>(bsum, offs);
    k_scan_final<<<SCAN_BLOCKS, 256, 0, stream>>>(deg, bsum, offs);
    k_scatter<<<eb, 256, 0, stream>>>(esrc, edst, ew, offs, deg, ep, E);
    k_zero<<<(N_NODES * F_OUT + 255) / 256, 256, 0, stream>>>((int*)o1, N_NODES * F_OUT);
    for (int half = 0; half < 2; ++half) {
      k_gemm1<<<gblocks, 256, 0, stream>>>(x, wT, h1, 128, half);
      k_agg1h<<<N_NODES / 4, 256, 0, stream>>>((const ushort2*)h1, offs, ep, b1, W2, o1, half);
    }
    k_agg2<<<N_NODES / 4, 256, 0, stream>>>(o1, offs, ep, b2, (float*)d_out);
  }
}

// Round 14
// 594.265 us; speedup vs baseline: 1.0329x; 1.0329x over previous
//
#include <hip/hip_runtime.h>

typedef short bf16x8 __attribute__((ext_vector_type(8)));
typedef float f32x4 __attribute__((ext_vector_type(4)));

constexpr int N_NODES = 50000;
constexpr int F_IN    = 512;
constexpr int F_HID   = 256;
constexpr int F_OUT   = 40;
constexpr int SCAN_BLOCKS = (N_NODES + 255) / 256;   // 196

__device__ __forceinline__ float bf2f(unsigned short u) {
  return __uint_as_float(((unsigned)u) << 16);
}
__device__ __forceinline__ unsigned short f2bf(float f) {
  unsigned x = __float_as_uint(f);
  x += 0x7FFFu + ((x >> 16) & 1u);      // RNE
  return (unsigned short)(x >> 16);
}

// pack 8 fp32 -> bf16x8 (RNE)
__device__ __forceinline__ bf16x8 cvt8(f32x4 a, f32x4 b) {
  bf16x8 o;
  o[0] = (short)f2bf(a[0]); o[1] = (short)f2bf(a[1]);
  o[2] = (short)f2bf(a[2]); o[3] = (short)f2bf(a[3]);
  o[4] = (short)f2bf(b[0]); o[5] = (short)f2bf(b[1]);
  o[6] = (short)f2bf(b[2]); o[7] = (short)f2bf(b[3]);
  return o;
}

// JAX threefry2x32, key=(0,42), PARTITIONABLE counter scheme (verified R8):
// element i -> pair (0, i); output = x0_final ^ x1_final; keep iff bit31==0.
__device__ __forceinline__ unsigned tf_rotl(unsigned x, int d) {
  return (x << d) | (x >> (32 - d));
}
__device__ __forceinline__ unsigned threefry_bits(unsigned i) {
  const unsigned k0 = 0u, k1 = 42u, k2 = 0x1BD11BDAu ^ 0u ^ 42u;
  unsigned x0 = 0u + k0, x1 = i + k1;
#define TF_R(r) { x0 += x1; x1 = tf_rotl(x1, (r)) ^ x0; }
  TF_R(13) TF_R(15) TF_R(26) TF_R(6)   x0 += k1; x1 += k2 + 1u;
  TF_R(17) TF_R(29) TF_R(16) TF_R(24)  x0 += k2; x1 += k0 + 2u;
  TF_R(13) TF_R(15) TF_R(26) TF_R(6)   x0 += k0; x1 += k1 + 3u;
  TF_R(17) TF_R(29) TF_R(16) TF_R(24)  x0 += k1; x1 += k2 + 4u;
  TF_R(13) TF_R(15) TF_R(26) TF_R(6)   x0 += k2; x1 += k0 + 5u;
#undef TF_R
  return x0 ^ x1;
}

__global__ void k_zero(int* __restrict__ p, int n) {
  int i = blockIdx.x * 256 + threadIdx.x;
  if (i < n) p[i] = 0;
}

// ---------------- CSR build (plain) ----------------
__global__ void k_hist(const int* __restrict__ dst, int* __restrict__ deg, int E) {
  int e = blockIdx.x * 256 + threadIdx.x;
  if (e < E) atomicAdd(&deg[dst[e]], 1);
}

__global__ __launch_bounds__(256) void k_scan_part(const int* __restrict__ deg,
                                                   int* __restrict__ bsum) {
  __shared__ int red[256];
  int t = threadIdx.x;
  int i = blockIdx.x * 256 + t;
  red[t] = (i < N_NODES) ? deg[i] : 0;
  __syncthreads();
#pragma unroll
  for (int off = 128; off > 0; off >>= 1) {
    if (t < off) red[t] += red[t + off];
    __syncthreads();
  }
  if (t == 0) bsum[blockIdx.x] = red[0];
}

__global__ __launch_bounds__(256) void k_scan_base(int* __restrict__ bsum,
                                                   int* __restrict__ offs) {
  __shared__ int sh[256];
  int t = threadIdx.x;
  int v = (t < SCAN_BLOCKS) ? bsum[t] : 0;
  sh[t] = v;
  __syncthreads();
#pragma unroll
  for (int off = 1; off < 256; off <<= 1) {
    int x = (t >= off) ? sh[t - off] : 0;
    __syncthreads();
    sh[t] += x;
    __syncthreads();
  }
  if (t < SCAN_BLOCKS) bsum[t] = sh[t] - v;        // exclusive block base
  if (t == 255) offs[N_NODES] = sh[255];           // == E
}

__global__ __launch_bounds__(256) void k_scan_final(int* __restrict__ deg,
                                                    const int* __restrict__ bsum,
                                                    int* __restrict__ offs) {
  __shared__ int sh[256];
  int t = threadIdx.x;
  int i = blockIdx.x * 256 + t;
  int v = (i < N_NODES) ? deg[i] : 0;
  sh[t] = v;
  __syncthreads();
#pragma unroll
  for (int off = 1; off < 256; off <<= 1) {
    int x = (t >= off) ? sh[t - off] : 0;
    __syncthreads();
    sh[t] += x;
    __syncthreads();
  }
  if (i < N_NODES) {
    offs[i] = bsum[blockIdx.x] + sh[t] - v;        // exclusive
    deg[i] = 0;                                    // becomes scatter cursor
  }
}

// packed edge: (src << 16) | bf16(weight)  (standalone, fallback path)
__global__ void k_scatter(const int* __restrict__ src, const int* __restrict__ dst,
                          const float* __restrict__ w,
                          const int* __restrict__ offs, int* __restrict__ cursor,
                          unsigned* __restrict__ ep, int E) {
  int e = blockIdx.x * 256 + threadIdx.x;
  if (e < E) {
    int d = dst[e];
    int pos = offs[d] + atomicAdd(&cursor[d], 1);
    if (pos >= 0 && pos < E)
      ep[pos] = ((unsigned)src[e] << 16) | (unsigned)f2bf(w[e]);
  }
}

// ---------------- W1 -> bf16 transpose (standalone, fallback path) -----------
__global__ void k_wt(const float* __restrict__ W1, unsigned short* __restrict__ wT) {
  int i = blockIdx.x * 256 + threadIdx.x;      // 131072 elements
  if (i < F_IN * F_HID) {
    int c = i >> 9, k = i & 511;
    wT[i] = f2bf(W1[(size_t)k * F_HID + c]);
  }
}

// ---------------- packed launch 1: k_wt ∥ k_hist (independent) ---------------
__global__ void k_wt_hist(const float* __restrict__ W1, unsigned short* __restrict__ wT,
                          const int* __restrict__ dst, int* __restrict__ deg,
                          int E, int wtBlocks) {
  int bid = blockIdx.x;
  if (bid < wtBlocks) {
    int i = bid * 256 + threadIdx.x;
    if (i < F_IN * F_HID) {
      int c = i >> 9, k = i & 511;
      wT[i] = f2bf(W1[(size_t)k * F_HID + c]);
    }
  } else {
    int e = (bid - wtBlocks) * 256 + threadIdx.x;
    if (e < E) atomicAdd(&deg[dst[e]], 1);
  }
}

// ---------------- layer-1 MFMA GEMM (standalone, fallback per-half) ----------
__global__ __launch_bounds__(256, 4) void k_gemm1(const float* __restrict__ X,
                                                  const unsigned short* __restrict__ wT,
                                                  unsigned short* __restrict__ out,
                                                  int ldh, int half) {
  int t = threadIdx.x;
  int wave = t >> 6, lane = t & 63, q = lane >> 4, r = lane & 15;
  int halfsel = half, tile = blockIdx.x;
  int r0 = tile * 64;
  int colbase = (ldh == 256) ? halfsel * 128 : 0;
  int arow = r0 + wave * 16 + r;
  if (arow > N_NODES - 1) arow = N_NODES - 1;
  const float* xrow = X + (size_t)arow * F_IN + q * 8;
  const unsigned short* bl = wT + (size_t)halfsel * 128 * F_IN + (size_t)r * F_IN + q * 8;
  f32x4 acc[8];
#pragma unroll
  for (int n = 0; n < 8; ++n) acc[n] = (f32x4){0.f, 0.f, 0.f, 0.f};
  bf16x8 BA[8], BB[8];
#pragma unroll
  for (int n = 0; n < 8; ++n)
    BA[n] = *(const bf16x8*)(bl + (size_t)n * 16 * F_IN);
#pragma unroll
  for (int k0 = 0; k0 < F_IN; k0 += 64) {
    f32x4 a0 = *(const f32x4*)(xrow + k0);
    f32x4 a1 = *(const f32x4*)(xrow + k0 + 4);
    f32x4 a2 = *(const f32x4*)(xrow + k0 + 32);
    f32x4 a3 = *(const f32x4*)(xrow + k0 + 36);
    bf16x8 A0 = cvt8(a0, a1);
    bf16x8 A1 = cvt8(a2, a3);
#pragma unroll
    for (int n = 0; n < 8; ++n)
      BB[n] = *(const bf16x8*)(bl + (size_t)n * 16 * F_IN + k0 + 32);
#pragma unroll
    for (int n = 0; n < 8; ++n)
      acc[n] = __builtin_amdgcn_mfma_f32_16x16x32_bf16(A0, BA[n], acc[n], 0, 0, 0);
    if (k0 + 64 < F_IN) {
#pragma unroll
      for (int n = 0; n < 8; ++n)
        BA[n] = *(const bf16x8*)(bl + (size_t)n * 16 * F_IN + k0 + 64);
    }
#pragma unroll
    for (int n = 0; n < 8; ++n)
      acc[n] = __builtin_amdgcn_mfma_f32_16x16x32_bf16(A1, BB[n], acc[n], 0, 0, 0);
  }
  int mrow = r0 + wave * 16 + q * 4;
#pragma unroll
  for (int n = 0; n < 8; ++n) {
#pragma unroll
    for (int tt = 0; tt < 4; ++tt) {
      int row = mrow + tt;
      if (row < N_NODES)
        out[(size_t)row * ldh + colbase + n * 16 + r] = f2bf(acc[n][tt]);
    }
  }
}

// ---------------- packed launch 2: fused gemm1 ∥ scatter (R12 best form) -----
// gemm blocks [0, gemmBlocks): R2-proven loop + R8 XCD half-pairing, ldh=256.
// scatter blocks [gemmBlocks, +eb) at the grid TAIL (R13 A/B: front placement
// cost 20+us via delayed gemm residency). WRITE ~125MB is dominated by the
// scatter's random 4B ep writes (sector writebacks) -- store-order-invariant.
__global__ __launch_bounds__(256, 4) void k_gemm1_scatter(
    const float* __restrict__ X, const unsigned short* __restrict__ wT,
    unsigned short* __restrict__ out,
    const int* __restrict__ src, const int* __restrict__ dst,
    const float* __restrict__ w, const int* __restrict__ offs,
    int* __restrict__ cursor, unsigned* __restrict__ ep,
    int E, int gemmBlocks) {
  int bid = blockIdx.x;
  if (bid >= gemmBlocks) {
    int e = (bid - gemmBlocks) * 256 + threadIdx.x;
    if (e < E) {
      int d = dst[e];
      int pos = offs[d] + atomicAdd(&cursor[d], 1);
      if (pos >= 0 && pos < E)
        ep[pos] = ((unsigned)src[e] << 16) | (unsigned)f2bf(w[e]);
    }
    return;
  }
  int t = threadIdx.x;
  int wave = t >> 6, lane = t & 63, q = lane >> 4, r = lane & 15;
  int halfsel = (bid >> 3) & 1;
  int tile = ((bid >> 4) << 3) + (bid & 7);
  int r0 = tile * 64;
  int colbase = halfsel * 128;
  int arow = r0 + wave * 16 + r;               // this lane's A row
  if (arow > N_NODES - 1) arow = N_NODES - 1;  // clamp (results discarded)
  const float* xrow = X + (size_t)arow * F_IN + q * 8;
  const unsigned short* bl = wT + (size_t)halfsel * 128 * F_IN + (size_t)r * F_IN + q * 8;
  f32x4 acc[8];
#pragma unroll
  for (int n = 0; n < 8; ++n) acc[n] = (f32x4){0.f, 0.f, 0.f, 0.f};

  bf16x8 BA[8], BB[8];
#pragma unroll
  for (int n = 0; n < 8; ++n)
    BA[n] = *(const bf16x8*)(bl + (size_t)n * 16 * F_IN);

#pragma unroll
  for (int k0 = 0; k0 < F_IN; k0 += 64) {
    f32x4 a0 = *(const f32x4*)(xrow + k0);
    f32x4 a1 = *(const f32x4*)(xrow + k0 + 4);
    f32x4 a2 = *(const f32x4*)(xrow + k0 + 32);
    f32x4 a3 = *(const f32x4*)(xrow + k0 + 36);
    bf16x8 A0 = cvt8(a0, a1);
    bf16x8 A1 = cvt8(a2, a3);
#pragma unroll
    for (int n = 0; n < 8; ++n)
      BB[n] = *(const bf16x8*)(bl + (size_t)n * 16 * F_IN + k0 + 32);
#pragma unroll
    for (int n = 0; n < 8; ++n)
      acc[n] = __builtin_amdgcn_mfma_f32_16x16x32_bf16(A0, BA[n], acc[n], 0, 0, 0);
    if (k0 + 64 < F_IN) {
#pragma unroll
      for (int n = 0; n < 8; ++n)
        BA[n] = *(const bf16x8*)(bl + (size_t)n * 16 * F_IN + k0 + 64);
    }
#pragma unroll
    for (int n = 0; n < 8; ++n)
      acc[n] = __builtin_amdgcn_mfma_f32_16x16x32_bf16(A1, BB[n], acc[n], 0, 0, 0);
  }
  // D: col = n*16 + r, row = wave*16 + q*4 + tt  (verified layout)
  int mrow = r0 + wave * 16 + q * 4;
#pragma unroll
  for (int n = 0; n < 8; ++n) {
#pragma unroll
    for (int tt = 0; tt < 4; ++tt) {
      int row = mrow + tt;
      if (row < N_NODES)
        out[(size_t)row * 256 + colbase + n * 16 + r] = f2bf(acc[n][tt]);
    }
  }
}

// ---------------- FUSED single-pass agg1 + gemm2 (full 256 cols) -------------
// Proven R5 form (173 us, structural floor: 340MB L2-miss @ ~2TB/s fabric on
// a random-graph gather -- R9's locality attempt was neutral). 4 scalar ep
// loads + 4 independent ushort4 gathers in flight; W2 staged bf16 in LDS
// (keeps VGPR at 40; removing it collapsed gather MLP in R6, 173->338 us).
__global__ __launch_bounds__(256) void k_agg1f(const ushort4* __restrict__ h14,
                                               const int* __restrict__ offs,
                                               const unsigned* __restrict__ ep,
                                               const float* __restrict__ b1,
                                               const float* __restrict__ W2,
                                               float* __restrict__ o1) {
  __shared__ unsigned short w2h[F_HID * F_OUT];  // 20 KB (row-major copy)
  __shared__ float hrow[4][F_HID];               // 4 KB
  int t = threadIdx.x;
  for (int i = t; i < F_HID * F_OUT; i += 256)
    w2h[i] = f2bf(W2[i]);                        // same layout, just bf16
  int wave = t >> 6, lane = t & 63;
  int wid = blockIdx.x * 4 + wave;
  int s0 = offs[wid], s1 = offs[wid + 1];
  float a0 = 0.f, a1 = 0.f, a2 = 0.f, a3 = 0.f;
  int e = s0;
  for (; e + 4 <= s1; e += 4) {
    unsigned p0 = ep[e], p1 = ep[e + 1], p2 = ep[e + 2], p3 = ep[e + 3];
    ushort4 v0 = h14[(size_t)(p0 >> 16) * 64 + lane];
    ushort4 v1 = h14[(size_t)(p1 >> 16) * 64 + lane];
    ushort4 v2 = h14[(size_t)(p2 >> 16) * 64 + lane];
    ushort4 v3 = h14[(size_t)(p3 >> 16) * 64 + lane];
    float w0 = bf2f((unsigned short)p0), w1 = bf2f((unsigned short)p1);
    float w2 = bf2f((unsigned short)p2), w3 = bf2f((unsigned short)p3);
    a0 = fmaf(w0, bf2f(v0.x), a0); a1 = fmaf(w0, bf2f(v0.y), a1);
    a2 = fmaf(w0, bf2f(v0.z), a2); a3 = fmaf(w0, bf2f(v0.w), a3);
    a0 = fmaf(w1, bf2f(v1.x), a0); a1 = fmaf(w1, bf2f(v1.y), a1);
    a2 = fmaf(w1, bf2f(v1.z), a2); a3 = fmaf(w1, bf2f(v1.w), a3);
    a0 = fmaf(w2, bf2f(v2.x), a0); a1 = fmaf(w2, bf2f(v2.y), a1);
    a2 = fmaf(w2, bf2f(v2.z), a2); a3 = fmaf(w2, bf2f(v2.w), a3);
    a0 = fmaf(w3, bf2f(v3.x), a0); a1 = fmaf(w3, bf2f(v3.y), a1);
    a2 = fmaf(w3, bf2f(v3.z), a2); a3 = fmaf(w3, bf2f(v3.w), a3);
  }
  for (; e < s1; ++e) {
    unsigned pe = ep[e];
    float w = bf2f((unsigned short)pe);
    ushort4 v = h14[(size_t)(pe >> 16) * 64 + lane];
    a0 = fmaf(w, bf2f(v.x), a0);
    a1 = fmaf(w, bf2f(v.y), a1);
    a2 = fmaf(w, bf2f(v.z), a2);
    a3 = fmaf(w, bf2f(v.w), a3);
  }
  int c0 = lane * 4;
  unsigned base = (unsigned)wid * 256u + (unsigned)c0;
  float r0 = fmaxf(a0 + b1[c0 + 0], 0.f);
  float r1 = fmaxf(a1 + b1[c0 + 1], 0.f);
  float r2 = fmaxf(a2 + b1[c0 + 2], 0.f);
  float r3 = fmaxf(a3 + b1[c0 + 3], 0.f);
  hrow[wave][c0 + 0] = (threefry_bits(base + 0u) >> 31) ? 0.f : r0 * 2.f;
  hrow[wave][c0 + 1] = (threefry_bits(base + 1u) >> 31) ? 0.f : r1 * 2.f;
  hrow[wave][c0 + 2] = (threefry_bits(base + 2u) >> 31) ? 0.f : r2 * 2.f;
  hrow[wave][c0 + 3] = (threefry_bits(base + 3u) >> 31) ? 0.f : r3 * 2.f;
  __syncthreads();                             // w2h + hrow visibility
  if (lane < F_OUT) {
    float acc = 0.f;
#pragma unroll 8
    for (int k = 0; k < F_HID; ++k)
      acc = fmaf(hrow[wave][k], bf2f(w2h[k * F_OUT + lane]), acc);
    o1[(size_t)wid * F_OUT + lane] = acc;      // single pass: direct store
  }
}

// ---------------- fallback: per-half agg1 (o1 accumulates) -------------------
__global__ __launch_bounds__(256) void k_agg1h(const ushort2* __restrict__ h1h2,
                                               const int* __restrict__ offs,
                                               const unsigned* __restrict__ ep,
                                               const float* __restrict__ b1,
                                               const float* __restrict__ W2,
                                               float* __restrict__ o1, int half) {
  __shared__ unsigned short w2h[128 * F_OUT];  // 10 KB
  __shared__ float hrow[4][128];               // 2 KB
  int t = threadIdx.x;
  for (int i = t; i < 128 * F_OUT; i += 256) {
    int k = i / F_OUT, j = i - k * F_OUT;
    w2h[i] = f2bf(W2[(size_t)(half * 128 + k) * F_OUT + j]);
  }
  int wave = t >> 6, lane = t & 63;
  int wid = blockIdx.x * 4 + wave;
  int s0 = offs[wid], s1 = offs[wid + 1];
  float a0 = 0.f, a1 = 0.f;
  int e = s0;
  for (; e + 4 <= s1; e += 4) {
    unsigned p0 = ep[e], p1 = ep[e + 1], p2 = ep[e + 2], p3 = ep[e + 3];
    ushort2 v0 = h1h2[(size_t)(p0 >> 16) * 64 + lane];
    ushort2 v1 = h1h2[(size_t)(p1 >> 16) * 64 + lane];
    ushort2 v2 = h1h2[(size_t)(p2 >> 16) * 64 + lane];
    ushort2 v3 = h1h2[(size_t)(p3 >> 16) * 64 + lane];
    float w0 = bf2f((unsigned short)p0), w1 = bf2f((unsigned short)p1);
    float w2 = bf2f((unsigned short)p2), w3 = bf2f((unsigned short)p3);
    a0 = fmaf(w0, bf2f(v0.x), a0); a1 = fmaf(w0, bf2f(v0.y), a1);
    a0 = fmaf(w1, bf2f(v1.x), a0); a1 = fmaf(w1, bf2f(v1.y), a1);
    a0 = fmaf(w2, bf2f(v2.x), a0); a1 = fmaf(w2, bf2f(v2.y), a1);
    a0 = fmaf(w3, bf2f(v3.x), a0); a1 = fmaf(w3, bf2f(v3.y), a1);
  }
  for (; e < s1; ++e) {
    unsigned pe = ep[e];
    float w = bf2f((unsigned short)pe);
    ushort2 v = h1h2[(size_t)(pe >> 16) * 64 + lane];
    a0 = fmaf(w, bf2f(v.x), a0);
    a1 = fmaf(w, bf2f(v.y), a1);
  }
  int c0 = lane * 2;
  int gc = half * 128 + c0;
  float r0 = fmaxf(a0 + b1[gc + 0], 0.f);
  float r1 = fmaxf(a1 + b1[gc + 1], 0.f);
  unsigned base = (unsigned)wid * 256u + (unsigned)gc;
  r0 = (threefry_bits(base + 0u) >> 31) ? 0.f : r0 * 2.f;   // keep iff u<0.5
  r1 = (threefry_bits(base + 1u) >> 31) ? 0.f : r1 * 2.f;
  hrow[wave][c0 + 0] = r0;
  hrow[wave][c0 + 1] = r1;
  __syncthreads();                             // w2h + hrow visibility
  if (lane < F_OUT) {
    float acc = 0.f;
#pragma unroll 8
    for (int k = 0; k < 128; ++k)
      acc = fmaf(hrow[wave][k], bf2f(w2h[k * F_OUT + lane]), acc);
    o1[(size_t)wid * F_OUT + lane] += acc;
  }
}

// ---------------- agg2: out[d] = sum_e w*o1[src] + b2 (fp32 out) --------------
// 8 scalar ep loads + 8 independent gathers in flight (R11, +9us).
__global__ __launch_bounds__(256) void k_agg2(const float* __restrict__ o1,
                                              const int* __restrict__ offs,
                                              const unsigned* __restrict__ ep,
                                              const float* __restrict__ b2,
                                              float* __restrict__ out) {
  int wid  = (blockIdx.x << 2) + (threadIdx.x >> 6);
  int lane = threadIdx.x & 63;
  if (lane >= F_OUT) return;
  int s0 = offs[wid], s1 = offs[wid + 1];
  float bias = b2[lane];
  float acc = 0.f;
  int e = s0;
  for (; e + 8 <= s1; e += 8) {
    unsigned p0 = ep[e],     p1 = ep[e + 1], p2 = ep[e + 2], p3 = ep[e + 3];
    unsigned p4 = ep[e + 4], p5 = ep[e + 5], p6 = ep[e + 6], p7 = ep[e + 7];
    float g0 = o1[(size_t)(p0 >> 16) * F_OUT + lane];
    float g1 = o1[(size_t)(p1 >> 16) * F_OUT + lane];
    float g2 = o1[(size_t)(p2 >> 16) * F_OUT + lane];
    float g3 = o1[(size_t)(p3 >> 16) * F_OUT + lane];
    float g4 = o1[(size_t)(p4 >> 16) * F_OUT + lane];
    float g5 = o1[(size_t)(p5 >> 16) * F_OUT + lane];
    float g6 = o1[(size_t)(p6 >> 16) * F_OUT + lane];
    float g7 = o1[(size_t)(p7 >> 16) * F_OUT + lane];
    acc = fmaf(bf2f((unsigned short)p0), g0, acc);
    acc = fmaf(bf2f((unsigned short)p1), g1, acc);
    acc = fmaf(bf2f((unsigned short)p2), g2, acc);
    acc = fmaf(bf2f((unsigned short)p3), g3, acc);
    acc = fmaf(bf2f((unsigned short)p4), g4, acc);
    acc = fmaf(bf2f((unsigned short)p5), g5, acc);
    acc = fmaf(bf2f((unsigned short)p6), g6, acc);
    acc = fmaf(bf2f((unsigned short)p7), g7, acc);
  }
  if (e + 4 <= s1) {
    unsigned p0 = ep[e], p1 = ep[e + 1], p2 = ep[e + 2], p3 = ep[e + 3];
    float g0 = o1[(size_t)(p0 >> 16) * F_OUT + lane];
    float g1 = o1[(size_t)(p1 >> 16) * F_OUT + lane];
    float g2 = o1[(size_t)(p2 >> 16) * F_OUT + lane];
    float g3 = o1[(size_t)(p3 >> 16) * F_OUT + lane];
    acc = fmaf(bf2f((unsigned short)p0), g0, acc);
    acc = fmaf(bf2f((unsigned short)p1), g1, acc);
    acc = fmaf(bf2f((unsigned short)p2), g2, acc);
    acc = fmaf(bf2f((unsigned short)p3), g3, acc);
    e += 4;
  }
  for (; e < s1; ++e) {
    unsigned pe = ep[e];
    acc = fmaf(bf2f((unsigned short)pe), o1[(size_t)(pe >> 16) * F_OUT + lane], acc);
  }
  out[(size_t)wid * F_OUT + lane] = acc + bias;
}

extern "C" void kernel_launch(void* const* d_in, const int* in_sizes, int n_in,
                              void* d_out, int out_size, void* d_ws, size_t ws_size,
                              hipStream_t stream) {
  const float* x    = (const float*)d_in[0];
  const int*   esrc = (const int*)d_in[1];
  const int*   edst = (const int*)d_in[2];
  const float* ew   = (const float*)d_in[3];
  const float* W1   = (const float*)d_in[4];
  const float* b1   = (const float*)d_in[5];
  const float* W2   = (const float*)d_in[6];
  const float* b2   = (const float*)d_in[7];
  const int E = in_sizes[1];

  auto rup = [](size_t b) { return (b + 255) & ~(size_t)255; };
  const size_t sz_h1full = rup((size_t)N_NODES * 256 * 2);   // 25.6 MB
  const size_t sz_h1half = rup((size_t)N_NODES * 128 * 2);   // 12.8 MB
  const size_t sz_o1     = rup((size_t)N_NODES * F_OUT * 4); // 8 MB
  const size_t sz_ep     = rup((size_t)E * 4);               // 6.4 MB
  const size_t sz_wT     = rup((size_t)F_IN * F_HID * 2);    // 262 KB
  const size_t sz_offs   = rup((size_t)(N_NODES + 1) * 4);
  const size_t sz_deg    = rup((size_t)N_NODES * 4);
  const size_t sz_bsum   = rup((size_t)SCAN_BLOCKS * 4);
  const size_t tail      = sz_o1 + sz_ep + sz_wT + sz_offs + sz_deg + sz_bsum;
  const bool   fused     = ws_size >= sz_h1full + tail;      // ~40.7 MB

  char* p = (char*)d_ws;
  auto alloc = [&](size_t bytes) { char* r = p; p += bytes; return r; };
  unsigned short* h1   = (unsigned short*)alloc(fused ? sz_h1full : sz_h1half);
  float*          o1   = (float*)alloc(sz_o1);
  unsigned*       ep   = (unsigned*)alloc(sz_ep);
  unsigned short* wT   = (unsigned short*)alloc(sz_wT);
  int*            offs = (int*)alloc(sz_offs);
  int*            deg  = (int*)alloc(sz_deg);
  int*            bsum = (int*)alloc(sz_bsum);

  int eb = (E + 255) / 256;
  int gblocks = (N_NODES + 63) / 64;           // 782
  int wtB = (F_IN * F_HID + 255) / 256;        // 512

  k_zero<<<(N_NODES + 255) / 256, 256, 0, stream>>>(deg, N_NODES);

  if (fused) {
    // L1: W1-transpose ∥ degree histogram (independent)
    k_wt_hist<<<wtB + eb, 256, 0, stream>>>(W1, wT, edst, deg, E, wtB);
    // L2-4: scan chain
    k_scan_part<<<SCAN_BLOCKS, 256, 0, stream>>>(deg, bsum);
    k_scan_base<<<1, 256, 0, stream>>>(bsum, offs);
    k_scan_final<<<SCAN_BLOCKS, 256, 0, stream>>>(deg, bsum, offs);
    // L5: fused gemm1 ∥ edge scatter (scatter at grid tail -- R13 A/B)
    int gpad = (gblocks + 7) & ~7;             // 784: bijective XCD pairing
    int gB = gpad * 2;                         // 1568 gemm blocks
    k_gemm1_scatter<<<gB + eb, 256, 0, stream>>>(x, wT, h1, esrc, edst, ew,
                                                 offs, deg, ep, E, gB);
    // L6-7
    k_agg1f<<<N_NODES / 4, 256, 0, stream>>>((const ushort4*)h1, offs, ep, b1, W2, o1);
    k_agg2<<<N_NODES / 4, 256, 0, stream>>>(o1, offs, ep, b2, (float*)d_out);
  } else {
    k_wt<<<wtB, 256, 0, stream>>>(W1, wT);
    k_hist<<<eb, 256, 0, stream>>>(edst, deg, E);
    k_scan_part<<<SCAN_BLOCKS, 256, 0, stream>>>(deg, bsum);
    k_scan_base<<<1, 256, 0, stream>>>(bsum, offs);
    k_scan_final<<<SCAN_BLOCKS, 256, 0, stream>>>(deg, bsum, offs);
    k_scatter<<<eb, 256, 0, stream>>>(esrc, edst, ew, offs, deg, ep, E);
    k_zero<<<(N_NODES * F_OUT + 255) / 256, 256, 0, stream>>>((int*)o1, N_NODES * F_OUT);
    for (int half = 0; half < 2; ++half) {
      k_gemm1<<<gblocks, 256, 0, stream>>>(x, wT, h1, 128, half);
      k_agg1h<<<N_NODES / 4, 256, 0, stream>>>((const ushort2*)h1, offs, ep, b1, W2, o1, half);
    }
    k_agg2<<<N_NODES / 4, 256, 0, stream>>>(o1, offs, ep, b2, (float*)d_out);
  }
}

// Round 15
// 589.508 us; speedup vs baseline: 1.0413x; 1.0081x over previous
//
#include <hip/hip_runtime.h>

typedef short bf16x8 __attribute__((ext_vector_type(8)));
typedef float f32x4 __attribute__((ext_vector_type(4)));

constexpr int N_NODES = 50000;
constexpr int F_IN    = 512;
constexpr int F_HID   = 256;
constexpr int F_OUT   = 40;
constexpr int SCAN_BLOCKS = (N_NODES + 255) / 256;   // 196

__device__ __forceinline__ float bf2f(unsigned short u) {
  return __uint_as_float(((unsigned)u) << 16);
}
__device__ __forceinline__ unsigned short f2bf(float f) {
  unsigned x = __float_as_uint(f);
  x += 0x7FFFu + ((x >> 16) & 1u);      // RNE
  return (unsigned short)(x >> 16);
}

// pack 8 fp32 -> bf16x8 (RNE)
__device__ __forceinline__ bf16x8 cvt8(f32x4 a, f32x4 b) {
  bf16x8 o;
  o[0] = (short)f2bf(a[0]); o[1] = (short)f2bf(a[1]);
  o[2] = (short)f2bf(a[2]); o[3] = (short)f2bf(a[3]);
  o[4] = (short)f2bf(b[0]); o[5] = (short)f2bf(b[1]);
  o[6] = (short)f2bf(b[2]); o[7] = (short)f2bf(b[3]);
  return o;
}

// JAX threefry2x32, key=(0,42), PARTITIONABLE counter scheme (verified R8):
// element i -> pair (0, i); output = x0_final ^ x1_final; keep iff bit31==0.
__device__ __forceinline__ unsigned tf_rotl(unsigned x, int d) {
  return (x << d) | (x >> (32 - d));
}
__device__ __forceinline__ unsigned threefry_bits(unsigned i) {
  const unsigned k0 = 0u, k1 = 42u, k2 = 0x1BD11BDAu ^ 0u ^ 42u;
  unsigned x0 = 0u + k0, x1 = i + k1;
#define TF_R(r) { x0 += x1; x1 = tf_rotl(x1, (r)) ^ x0; }
  TF_R(13) TF_R(15) TF_R(26) TF_R(6)   x0 += k1; x1 += k2 + 1u;
  TF_R(17) TF_R(29) TF_R(16) TF_R(24)  x0 += k2; x1 += k0 + 2u;
  TF_R(13) TF_R(15) TF_R(26) TF_R(6)   x0 += k0; x1 += k1 + 3u;
  TF_R(17) TF_R(29) TF_R(16) TF_R(24)  x0 += k1; x1 += k2 + 4u;
  TF_R(13) TF_R(15) TF_R(26) TF_R(6)   x0 += k2; x1 += k0 + 5u;
#undef TF_R
  return x0 ^ x1;
}

__global__ void k_zero(int* __restrict__ p, int n) {
  int i = blockIdx.x * 256 + threadIdx.x;
  if (i < n) p[i] = 0;
}

// ---------------- CSR build (plain) ----------------
__global__ void k_hist(const int* __restrict__ dst, int* __restrict__ deg, int E) {
  int e = blockIdx.x * 256 + threadIdx.x;
  if (e < E) atomicAdd(&deg[dst[e]], 1);
}

__global__ __launch_bounds__(256) void k_scan_part(const int* __restrict__ deg,
                                                   int* __restrict__ bsum) {
  __shared__ int red[256];
  int t = threadIdx.x;
  int i = blockIdx.x * 256 + t;
  red[t] = (i < N_NODES) ? deg[i] : 0;
  __syncthreads();
#pragma unroll
  for (int off = 128; off > 0; off >>= 1) {
    if (t < off) red[t] += red[t + off];
    __syncthreads();
  }
  if (t == 0) bsum[blockIdx.x] = red[0];
}

__global__ __launch_bounds__(256) void k_scan_base(int* __restrict__ bsum,
                                                   int* __restrict__ offs) {
  __shared__ int sh[256];
  int t = threadIdx.x;
  int v = (t < SCAN_BLOCKS) ? bsum[t] : 0;
  sh[t] = v;
  __syncthreads();
#pragma unroll
  for (int off = 1; off < 256; off <<= 1) {
    int x = (t >= off) ? sh[t - off] : 0;
    __syncthreads();
    sh[t] += x;
    __syncthreads();
  }
  if (t < SCAN_BLOCKS) bsum[t] = sh[t] - v;        // exclusive block base
  if (t == 255) offs[N_NODES] = sh[255];           // == E
}

__global__ __launch_bounds__(256) void k_scan_final(int* __restrict__ deg,
                                                    const int* __restrict__ bsum,
                                                    int* __restrict__ offs) {
  __shared__ int sh[256];
  int t = threadIdx.x;
  int i = blockIdx.x * 256 + t;
  int v = (i < N_NODES) ? deg[i] : 0;
  sh[t] = v;
  __syncthreads();
#pragma unroll
  for (int off = 1; off < 256; off <<= 1) {
    int x = (t >= off) ? sh[t - off] : 0;
    __syncthreads();
    sh[t] += x;
    __syncthreads();
  }
  if (i < N_NODES) {
    offs[i] = bsum[blockIdx.x] + sh[t] - v;        // exclusive
    deg[i] = 0;                                    // becomes scatter cursor
  }
}

// packed edge: (src << 16) | bf16(weight)  (standalone, fallback path)
__global__ void k_scatter(const int* __restrict__ src, const int* __restrict__ dst,
                          const float* __restrict__ w,
                          const int* __restrict__ offs, int* __restrict__ cursor,
                          unsigned* __restrict__ ep, int E) {
  int e = blockIdx.x * 256 + threadIdx.x;
  if (e < E) {
    int d = dst[e];
    int pos = offs[d] + atomicAdd(&cursor[d], 1);
    if (pos >= 0 && pos < E)
      ep[pos] = ((unsigned)src[e] << 16) | (unsigned)f2bf(w[e]);
  }
}

// ---------------- W1 -> bf16 transpose (standalone, fallback path) -----------
__global__ void k_wt(const float* __restrict__ W1, unsigned short* __restrict__ wT) {
  int i = blockIdx.x * 256 + threadIdx.x;      // 131072 elements
  if (i < F_IN * F_HID) {
    int c = i >> 9, k = i & 511;
    wT[i] = f2bf(W1[(size_t)k * F_HID + c]);
  }
}

// ---------------- packed launch 1: k_wt ∥ k_hist (independent) ---------------
__global__ void k_wt_hist(const float* __restrict__ W1, unsigned short* __restrict__ wT,
                          const int* __restrict__ dst, int* __restrict__ deg,
                          int E, int wtBlocks) {
  int bid = blockIdx.x;
  if (bid < wtBlocks) {
    int i = bid * 256 + threadIdx.x;
    if (i < F_IN * F_HID) {
      int c = i >> 9, k = i & 511;
      wT[i] = f2bf(W1[(size_t)k * F_HID + c]);
    }
  } else {
    int e = (bid - wtBlocks) * 256 + threadIdx.x;
    if (e < E) atomicAdd(&deg[dst[e]], 1);
  }
}

// ---------------- layer-1 MFMA GEMM (standalone, fallback per-half) ----------
__global__ __launch_bounds__(256, 4) void k_gemm1(const float* __restrict__ X,
                                                  const unsigned short* __restrict__ wT,
                                                  unsigned short* __restrict__ out,
                                                  int ldh, int half) {
  int t = threadIdx.x;
  int wave = t >> 6, lane = t & 63, q = lane >> 4, r = lane & 15;
  int halfsel = half, tile = blockIdx.x;
  int r0 = tile * 64;
  int colbase = (ldh == 256) ? halfsel * 128 : 0;
  int arow = r0 + wave * 16 + r;
  if (arow > N_NODES - 1) arow = N_NODES - 1;
  const float* xrow = X + (size_t)arow * F_IN + q * 8;
  const unsigned short* bl = wT + (size_t)halfsel * 128 * F_IN + (size_t)r * F_IN + q * 8;
  f32x4 acc[8];
#pragma unroll
  for (int n = 0; n < 8; ++n) acc[n] = (f32x4){0.f, 0.f, 0.f, 0.f};
  bf16x8 BA[8], BB[8];
#pragma unroll
  for (int n = 0; n < 8; ++n)
    BA[n] = *(const bf16x8*)(bl + (size_t)n * 16 * F_IN);
#pragma unroll
  for (int k0 = 0; k0 < F_IN; k0 += 64) {
    f32x4 a0 = *(const f32x4*)(xrow + k0);
    f32x4 a1 = *(const f32x4*)(xrow + k0 + 4);
    f32x4 a2 = *(const f32x4*)(xrow + k0 + 32);
    f32x4 a3 = *(const f32x4*)(xrow + k0 + 36);
    bf16x8 A0 = cvt8(a0, a1);
    bf16x8 A1 = cvt8(a2, a3);
#pragma unroll
    for (int n = 0; n < 8; ++n)
      BB[n] = *(const bf16x8*)(bl + (size_t)n * 16 * F_IN + k0 + 32);
#pragma unroll
    for (int n = 0; n < 8; ++n)
      acc[n] = __builtin_amdgcn_mfma_f32_16x16x32_bf16(A0, BA[n], acc[n], 0, 0, 0);
    if (k0 + 64 < F_IN) {
#pragma unroll
      for (int n = 0; n < 8; ++n)
        BA[n] = *(const bf16x8*)(bl + (size_t)n * 16 * F_IN + k0 + 64);
    }
#pragma unroll
    for (int n = 0; n < 8; ++n)
      acc[n] = __builtin_amdgcn_mfma_f32_16x16x32_bf16(A1, BB[n], acc[n], 0, 0, 0);
  }
  int mrow = r0 + wave * 16 + q * 4;
#pragma unroll
  for (int n = 0; n < 8; ++n) {
#pragma unroll
    for (int tt = 0; tt < 4; ++tt) {
      int row = mrow + tt;
      if (row < N_NODES)
        out[(size_t)row * ldh + colbase + n * 16 + r] = f2bf(acc[n][tt]);
    }
  }
}

// ---------------- packed launch 2: fused gemm1 ∥ scatter (R12 best form) -----
// gemm blocks [0, gemmBlocks): R2-proven loop + R8 XCD half-pairing, ldh=256.
// scatter blocks [gemmBlocks, +eb) at the grid TAIL (R13 A/B: front placement
// cost 20+us via delayed gemm residency). WRITE ~125MB is dominated by the
// scatter's random 4B ep writes (sector writebacks) -- store-order-invariant.
__global__ __launch_bounds__(256, 4) void k_gemm1_scatter(
    const float* __restrict__ X, const unsigned short* __restrict__ wT,
    unsigned short* __restrict__ out,
    const int* __restrict__ src, const int* __restrict__ dst,
    const float* __restrict__ w, const int* __restrict__ offs,
    int* __restrict__ cursor, unsigned* __restrict__ ep,
    int E, int gemmBlocks) {
  int bid = blockIdx.x;
  if (bid >= gemmBlocks) {
    int e = (bid - gemmBlocks) * 256 + threadIdx.x;
    if (e < E) {
      int d = dst[e];
      int pos = offs[d] + atomicAdd(&cursor[d], 1);
      if (pos >= 0 && pos < E)
        ep[pos] = ((unsigned)src[e] << 16) | (unsigned)f2bf(w[e]);
    }
    return;
  }
  int t = threadIdx.x;
  int wave = t >> 6, lane = t & 63, q = lane >> 4, r = lane & 15;
  int halfsel = (bid >> 3) & 1;
  int tile = ((bid >> 4) << 3) + (bid & 7);
  int r0 = tile * 64;
  int colbase = halfsel * 128;
  int arow = r0 + wave * 16 + r;               // this lane's A row
  if (arow > N_NODES - 1) arow = N_NODES - 1;  // clamp (results discarded)
  const float* xrow = X + (size_t)arow * F_IN + q * 8;
  const unsigned short* bl = wT + (size_t)halfsel * 128 * F_IN + (size_t)r * F_IN + q * 8;
  f32x4 acc[8];
#pragma unroll
  for (int n = 0; n < 8; ++n) acc[n] = (f32x4){0.f, 0.f, 0.f, 0.f};

  bf16x8 BA[8], BB[8];
#pragma unroll
  for (int n = 0; n < 8; ++n)
    BA[n] = *(const bf16x8*)(bl + (size_t)n * 16 * F_IN);

#pragma unroll
  for (int k0 = 0; k0 < F_IN; k0 += 64) {
    f32x4 a0 = *(const f32x4*)(xrow + k0);
    f32x4 a1 = *(const f32x4*)(xrow + k0 + 4);
    f32x4 a2 = *(const f32x4*)(xrow + k0 + 32);
    f32x4 a3 = *(const f32x4*)(xrow + k0 + 36);
    bf16x8 A0 = cvt8(a0, a1);
    bf16x8 A1 = cvt8(a2, a3);
#pragma unroll
    for (int n = 0; n < 8; ++n)
      BB[n] = *(const bf16x8*)(bl + (size_t)n * 16 * F_IN + k0 + 32);
#pragma unroll
    for (int n = 0; n < 8; ++n)
      acc[n] = __builtin_amdgcn_mfma_f32_16x16x32_bf16(A0, BA[n], acc[n], 0, 0, 0);
    if (k0 + 64 < F_IN) {
#pragma unroll
      for (int n = 0; n < 8; ++n)
        BA[n] = *(const bf16x8*)(bl + (size_t)n * 16 * F_IN + k0 + 64);
    }
#pragma unroll
    for (int n = 0; n < 8; ++n)
      acc[n] = __builtin_amdgcn_mfma_f32_16x16x32_bf16(A1, BB[n], acc[n], 0, 0, 0);
  }
  // D: col = n*16 + r, row = wave*16 + q*4 + tt  (verified layout)
  int mrow = r0 + wave * 16 + q * 4;
#pragma unroll
  for (int n = 0; n < 8; ++n) {
#pragma unroll
    for (int tt = 0; tt < 4; ++tt) {
      int row = mrow + tt;
      if (row < N_NODES)
        out[(size_t)row * 256 + colbase + n * 16 + r] = f2bf(acc[n][tt]);
    }
  }
}

// ---------------- FUSED single-pass agg1 + gemm2 (full 256 cols) -------------
// Proven R5 form (173 us, structural floor: 340MB L2-miss @ ~2TB/s fabric on
// a random-graph gather -- R9's locality attempt was neutral). 4 scalar ep
// loads + 4 independent ushort4 gathers in flight; W2 staged bf16 in LDS
// (keeps VGPR at 40; removing it collapsed gather MLP in R6, 173->338 us).
// o1 stored BF16 (R15): halves agg2's gather bytes; o1 table 8MB->4MB
// (= one XCD L2). Error contribution ~3e-4 abs, under the existing 2e-3.
__global__ __launch_bounds__(256) void k_agg1f(const ushort4* __restrict__ h14,
                                               const int* __restrict__ offs,
                                               const unsigned* __restrict__ ep,
                                               const float* __restrict__ b1,
                                               const float* __restrict__ W2,
                                               unsigned short* __restrict__ o1h) {
  __shared__ unsigned short w2h[F_HID * F_OUT];  // 20 KB (row-major copy)
  __shared__ float hrow[4][F_HID];               // 4 KB
  int t = threadIdx.x;
  for (int i = t; i < F_HID * F_OUT; i += 256)
    w2h[i] = f2bf(W2[i]);                        // same layout, just bf16
  int wave = t >> 6, lane = t & 63;
  int wid = blockIdx.x * 4 + wave;
  int s0 = offs[wid], s1 = offs[wid + 1];
  float a0 = 0.f, a1 = 0.f, a2 = 0.f, a3 = 0.f;
  int e = s0;
  for (; e + 4 <= s1; e += 4) {
    unsigned p0 = ep[e], p1 = ep[e + 1], p2 = ep[e + 2], p3 = ep[e + 3];
    ushort4 v0 = h14[(size_t)(p0 >> 16) * 64 + lane];
    ushort4 v1 = h14[(size_t)(p1 >> 16) * 64 + lane];
    ushort4 v2 = h14[(size_t)(p2 >> 16) * 64 + lane];
    ushort4 v3 = h14[(size_t)(p3 >> 16) * 64 + lane];
    float w0 = bf2f((unsigned short)p0), w1 = bf2f((unsigned short)p1);
    float w2 = bf2f((unsigned short)p2), w3 = bf2f((unsigned short)p3);
    a0 = fmaf(w0, bf2f(v0.x), a0); a1 = fmaf(w0, bf2f(v0.y), a1);
    a2 = fmaf(w0, bf2f(v0.z), a2); a3 = fmaf(w0, bf2f(v0.w), a3);
    a0 = fmaf(w1, bf2f(v1.x), a0); a1 = fmaf(w1, bf2f(v1.y), a1);
    a2 = fmaf(w1, bf2f(v1.z), a2); a3 = fmaf(w1, bf2f(v1.w), a3);
    a0 = fmaf(w2, bf2f(v2.x), a0); a1 = fmaf(w2, bf2f(v2.y), a1);
    a2 = fmaf(w2, bf2f(v2.z), a2); a3 = fmaf(w2, bf2f(v2.w), a3);
    a0 = fmaf(w3, bf2f(v3.x), a0); a1 = fmaf(w3, bf2f(v3.y), a1);
    a2 = fmaf(w3, bf2f(v3.z), a2); a3 = fmaf(w3, bf2f(v3.w), a3);
  }
  for (; e < s1; ++e) {
    unsigned pe = ep[e];
    float w = bf2f((unsigned short)pe);
    ushort4 v = h14[(size_t)(pe >> 16) * 64 + lane];
    a0 = fmaf(w, bf2f(v.x), a0);
    a1 = fmaf(w, bf2f(v.y), a1);
    a2 = fmaf(w, bf2f(v.z), a2);
    a3 = fmaf(w, bf2f(v.w), a3);
  }
  int c0 = lane * 4;
  unsigned base = (unsigned)wid * 256u + (unsigned)c0;
  float r0 = fmaxf(a0 + b1[c0 + 0], 0.f);
  float r1 = fmaxf(a1 + b1[c0 + 1], 0.f);
  float r2 = fmaxf(a2 + b1[c0 + 2], 0.f);
  float r3 = fmaxf(a3 + b1[c0 + 3], 0.f);
  hrow[wave][c0 + 0] = (threefry_bits(base + 0u) >> 31) ? 0.f : r0 * 2.f;
  hrow[wave][c0 + 1] = (threefry_bits(base + 1u) >> 31) ? 0.f : r1 * 2.f;
  hrow[wave][c0 + 2] = (threefry_bits(base + 2u) >> 31) ? 0.f : r2 * 2.f;
  hrow[wave][c0 + 3] = (threefry_bits(base + 3u) >> 31) ? 0.f : r3 * 2.f;
  __syncthreads();                             // w2h + hrow visibility
  if (lane < F_OUT) {
    float acc = 0.f;
#pragma unroll 8
    for (int k = 0; k < F_HID; ++k)
      acc = fmaf(hrow[wave][k], bf2f(w2h[k * F_OUT + lane]), acc);
    o1h[(size_t)wid * F_OUT + lane] = f2bf(acc);   // bf16 store (R15)
  }
}

// ---------------- fallback: per-half agg1 (o1 accumulates, fp32) -------------
__global__ __launch_bounds__(256) void k_agg1h(const ushort2* __restrict__ h1h2,
                                               const int* __restrict__ offs,
                                               const unsigned* __restrict__ ep,
                                               const float* __restrict__ b1,
                                               const float* __restrict__ W2,
                                               float* __restrict__ o1, int half) {
  __shared__ unsigned short w2h[128 * F_OUT];  // 10 KB
  __shared__ float hrow[4][128];               // 2 KB
  int t = threadIdx.x;
  for (int i = t; i < 128 * F_OUT; i += 256) {
    int k = i / F_OUT, j = i - k * F_OUT;
    w2h[i] = f2bf(W2[(size_t)(half * 128 + k) * F_OUT + j]);
  }
  int wave = t >> 6, lane = t & 63;
  int wid = blockIdx.x * 4 + wave;
  int s0 = offs[wid], s1 = offs[wid + 1];
  float a0 = 0.f, a1 = 0.f;
  int e = s0;
  for (; e + 4 <= s1; e += 4) {
    unsigned p0 = ep[e], p1 = ep[e + 1], p2 = ep[e + 2], p3 = ep[e + 3];
    ushort2 v0 = h1h2[(size_t)(p0 >> 16) * 64 + lane];
    ushort2 v1 = h1h2[(size_t)(p1 >> 16) * 64 + lane];
    ushort2 v2 = h1h2[(size_t)(p2 >> 16) * 64 + lane];
    ushort2 v3 = h1h2[(size_t)(p3 >> 16) * 64 + lane];
    float w0 = bf2f((unsigned short)p0), w1 = bf2f((unsigned short)p1);
    float w2 = bf2f((unsigned short)p2), w3 = bf2f((unsigned short)p3);
    a0 = fmaf(w0, bf2f(v0.x), a0); a1 = fmaf(w0, bf2f(v0.y), a1);
    a0 = fmaf(w1, bf2f(v1.x), a0); a1 = fmaf(w1, bf2f(v1.y), a1);
    a0 = fmaf(w2, bf2f(v2.x), a0); a1 = fmaf(w2, bf2f(v2.y), a1);
    a0 = fmaf(w3, bf2f(v3.x), a0); a1 = fmaf(w3, bf2f(v3.y), a1);
  }
  for (; e < s1; ++e) {
    unsigned pe = ep[e];
    float w = bf2f((unsigned short)pe);
    ushort2 v = h1h2[(size_t)(pe >> 16) * 64 + lane];
    a0 = fmaf(w, bf2f(v.x), a0);
    a1 = fmaf(w, bf2f(v.y), a1);
  }
  int c0 = lane * 2;
  int gc = half * 128 + c0;
  float r0 = fmaxf(a0 + b1[gc + 0], 0.f);
  float r1 = fmaxf(a1 + b1[gc + 1], 0.f);
  unsigned base = (unsigned)wid * 256u + (unsigned)gc;
  r0 = (threefry_bits(base + 0u) >> 31) ? 0.f : r0 * 2.f;   // keep iff u<0.5
  r1 = (threefry_bits(base + 1u) >> 31) ? 0.f : r1 * 2.f;
  hrow[wave][c0 + 0] = r0;
  hrow[wave][c0 + 1] = r1;
  __syncthreads();                             // w2h + hrow visibility
  if (lane < F_OUT) {
    float acc = 0.f;
#pragma unroll 8
    for (int k = 0; k < 128; ++k)
      acc = fmaf(hrow[wave][k], bf2f(w2h[k * F_OUT + lane]), acc);
    o1[(size_t)wid * F_OUT + lane] += acc;
  }
}

// ---------------- agg2 (bf16 o1): out[d] = sum_e w*o1[src] + b2 --------------
// 8 scalar ep loads + 8 independent 2B gathers in flight (R11 structure).
__global__ __launch_bounds__(256) void k_agg2h(const unsigned short* __restrict__ o1h,
                                               const int* __restrict__ offs,
                                               const unsigned* __restrict__ ep,
                                               const float* __restrict__ b2,
                                               float* __restrict__ out) {
  int wid  = (blockIdx.x << 2) + (threadIdx.x >> 6);
  int lane = threadIdx.x & 63;
  if (lane >= F_OUT) return;
  int s0 = offs[wid], s1 = offs[wid + 1];
  float bias = b2[lane];
  float acc = 0.f;
  int e = s0;
  for (; e + 8 <= s1; e += 8) {
    unsigned p0 = ep[e],     p1 = ep[e + 1], p2 = ep[e + 2], p3 = ep[e + 3];
    unsigned p4 = ep[e + 4], p5 = ep[e + 5], p6 = ep[e + 6], p7 = ep[e + 7];
    unsigned short g0 = o1h[(size_t)(p0 >> 16) * F_OUT + lane];
    unsigned short g1 = o1h[(size_t)(p1 >> 16) * F_OUT + lane];
    unsigned short g2 = o1h[(size_t)(p2 >> 16) * F_OUT + lane];
    unsigned short g3 = o1h[(size_t)(p3 >> 16) * F_OUT + lane];
    unsigned short g4 = o1h[(size_t)(p4 >> 16) * F_OUT + lane];
    unsigned short g5 = o1h[(size_t)(p5 >> 16) * F_OUT + lane];
    unsigned short g6 = o1h[(size_t)(p6 >> 16) * F_OUT + lane];
    unsigned short g7 = o1h[(size_t)(p7 >> 16) * F_OUT + lane];
    acc = fmaf(bf2f((unsigned short)p0), bf2f(g0), acc);
    acc = fmaf(bf2f((unsigned short)p1), bf2f(g1), acc);
    acc = fmaf(bf2f((unsigned short)p2), bf2f(g2), acc);
    acc = fmaf(bf2f((unsigned short)p3), bf2f(g3), acc);
    acc = fmaf(bf2f((unsigned short)p4), bf2f(g4), acc);
    acc = fmaf(bf2f((unsigned short)p5), bf2f(g5), acc);
    acc = fmaf(bf2f((unsigned short)p6), bf2f(g6), acc);
    acc = fmaf(bf2f((unsigned short)p7), bf2f(g7), acc);
  }
  if (e + 4 <= s1) {
    unsigned p0 = ep[e], p1 = ep[e + 1], p2 = ep[e + 2], p3 = ep[e + 3];
    unsigned short g0 = o1h[(size_t)(p0 >> 16) * F_OUT + lane];
    unsigned short g1 = o1h[(size_t)(p1 >> 16) * F_OUT + lane];
    unsigned short g2 = o1h[(size_t)(p2 >> 16) * F_OUT + lane];
    unsigned short g3 = o1h[(size_t)(p3 >> 16) * F_OUT + lane];
    acc = fmaf(bf2f((unsigned short)p0), bf2f(g0), acc);
    acc = fmaf(bf2f((unsigned short)p1), bf2f(g1), acc);
    acc = fmaf(bf2f((unsigned short)p2), bf2f(g2), acc);
    acc = fmaf(bf2f((unsigned short)p3), bf2f(g3), acc);
    e += 4;
  }
  for (; e < s1; ++e) {
    unsigned pe = ep[e];
    acc = fmaf(bf2f((unsigned short)pe),
               bf2f(o1h[(size_t)(pe >> 16) * F_OUT + lane]), acc);
  }
  out[(size_t)wid * F_OUT + lane] = acc + bias;
}

// ---------------- agg2 (fp32 o1, fallback path) ------------------------------
__global__ __launch_bounds__(256) void k_agg2(const float* __restrict__ o1,
                                              const int* __restrict__ offs,
                                              const unsigned* __restrict__ ep,
                                              const float* __restrict__ b2,
                                              float* __restrict__ out) {
  int wid  = (blockIdx.x << 2) + (threadIdx.x >> 6);
  int lane = threadIdx.x & 63;
  if (lane >= F_OUT) return;
  int s0 = offs[wid], s1 = offs[wid + 1];
  float bias = b2[lane];
  float acc = 0.f;
  int e = s0;
  for (; e + 4 <= s1; e += 4) {
    unsigned p0 = ep[e], p1 = ep[e + 1], p2 = ep[e + 2], p3 = ep[e + 3];
    float g0 = o1[(size_t)(p0 >> 16) * F_OUT + lane];
    float g1 = o1[(size_t)(p1 >> 16) * F_OUT + lane];
    float g2 = o1[(size_t)(p2 >> 16) * F_OUT + lane];
    float g3 = o1[(size_t)(p3 >> 16) * F_OUT + lane];
    acc = fmaf(bf2f((unsigned short)p0), g0, acc);
    acc = fmaf(bf2f((unsigned short)p1), g1, acc);
    acc = fmaf(bf2f((unsigned short)p2), g2, acc);
    acc = fmaf(bf2f((unsigned short)p3), g3, acc);
  }
  for (; e < s1; ++e) {
    unsigned pe = ep[e];
    acc = fmaf(bf2f((unsigned short)pe), o1[(size_t)(pe >> 16) * F_OUT + lane], acc);
  }
  out[(size_t)wid * F_OUT + lane] = acc + bias;
}

extern "C" void kernel_launch(void* const* d_in, const int* in_sizes, int n_in,
                              void* d_out, int out_size, void* d_ws, size_t ws_size,
                              hipStream_t stream) {
  const float* x    = (const float*)d_in[0];
  const int*   esrc = (const int*)d_in[1];
  const int*   edst = (const int*)d_in[2];
  const float* ew   = (const float*)d_in[3];
  const float* W1   = (const float*)d_in[4];
  const float* b1   = (const float*)d_in[5];
  const float* W2   = (const float*)d_in[6];
  const float* b2   = (const float*)d_in[7];
  const int E = in_sizes[1];

  auto rup = [](size_t b) { return (b + 255) & ~(size_t)255; };
  const size_t sz_h1full = rup((size_t)N_NODES * 256 * 2);   // 25.6 MB
  const size_t sz_h1half = rup((size_t)N_NODES * 128 * 2);   // 12.8 MB
  const size_t sz_o1     = rup((size_t)N_NODES * F_OUT * 4); // 8 MB (fp32 superset)
  const size_t sz_ep     = rup((size_t)E * 4);               // 6.4 MB
  const size_t sz_wT     = rup((size_t)F_IN * F_HID * 2);    // 262 KB
  const size_t sz_offs   = rup((size_t)(N_NODES + 1) * 4);
  const size_t sz_deg    = rup((size_t)N_NODES * 4);
  const size_t sz_bsum   = rup((size_t)SCAN_BLOCKS * 4);
  const size_t tail      = sz_o1 + sz_ep + sz_wT + sz_offs + sz_deg + sz_bsum;
  const bool   fused     = ws_size >= sz_h1full + tail;      // ~40.7 MB

  char* p = (char*)d_ws;
  auto alloc = [&](size_t bytes) { char* r = p; p += bytes; return r; };
  unsigned short* h1   = (unsigned short*)alloc(fused ? sz_h1full : sz_h1half);
  float*          o1   = (float*)alloc(sz_o1);     // fused path uses first 4MB as bf16
  unsigned*       ep   = (unsigned*)alloc(sz_ep);
  unsigned short* wT   = (unsigned short*)alloc(sz_wT);
  int*            offs = (int*)alloc(sz_offs);
  int*            deg  = (int*)alloc(sz_deg);
  int*            bsum = (int*)alloc(sz_bsum);

  int eb = (E + 255) / 256;
  int gblocks = (N_NODES + 63) / 64;           // 782
  int wtB = (F_IN * F_HID + 255) / 256;        // 512

  k_zero<<<(N_NODES + 255) / 256, 256, 0, stream>>>(deg, N_NODES);

  if (fused) {
    // L1: W1-transpose ∥ degree histogram (independent)
    k_wt_hist<<<wtB + eb, 256, 0, stream>>>(W1, wT, edst, deg, E, wtB);
    // L2-4: scan chain
    k_scan_part<<<SCAN_BLOCKS, 256, 0, stream>>>(deg, bsum);
    k_scan_base<<<1, 256, 0, stream>>>(bsum, offs);
    k_scan_final<<<SCAN_BLOCKS, 256, 0, stream>>>(deg, bsum, offs);
    // L5: fused gemm1 ∥ edge scatter (scatter at grid tail -- R13 A/B)
    int gpad = (gblocks + 7) & ~7;             // 784: bijective XCD pairing
    int gB = gpad * 2;                         // 1568 gemm blocks
    k_gemm1_scatter<<<gB + eb, 256, 0, stream>>>(x, wT, h1, esrc, edst, ew,
                                                 offs, deg, ep, E, gB);
    // L6-7: o1 in bf16 (4MB, one-XCD-L2-resident)
    unsigned short* o1h = (unsigned short*)o1;
    k_agg1f<<<N_NODES / 4, 256, 0, stream>>>((const ushort4*)h1, offs, ep, b1, W2, o1h);
    k_agg2h<<<N_NODES / 4, 256, 0, stream>>>(o1h, offs, ep, b2, (float*)d_out);
  } else {
    k_wt<<<wtB, 256, 0, stream>>>(W1, wT);
    k_hist<<<eb, 256, 0, stream>>>(edst, deg, E);
    k_scan_part<<<SCAN_BLOCKS, 256, 0, stream>>>(deg, bsum);
    k_scan_base<<<1, 256, 0, stream>>>(bsum, offs);
    k_scan_final<<<SCAN_BLOCKS, 256, 0, stream>>>(deg, bsum, offs);
    k_scatter<<<eb, 256, 0, stream>>>(esrc, edst, ew, offs, deg, ep, E);
    k_zero<<<(N_NODES * F_OUT + 255) / 256, 256, 0, stream>>>((int*)o1, N_NODES * F_OUT);
    for (int half = 0; half < 2; ++half) {
      k_gemm1<<<gblocks, 256, 0, stream>>>(x, wT, h1, 128, half);
      k_agg1h<<<N_NODES / 4, 256, 0, stream>>>((const ushort2*)h1, offs, ep, b1, W2, o1, half);
    }
    k_agg2<<<N_NODES / 4, 256, 0, stream>>>(o1, offs, ep, b2, (float*)d_out);
  }
}